// Round 6
// baseline (184.172 us; speedup 1.0000x reference)
//
#include <hip/hip_runtime.h>

#define BLOCK 256
#define VPT 4   // float4s per thread, lane-contiguous, straight-line

typedef float f32x4 __attribute__((ext_vector_type(4)));

// out[b][j] = x[b][(j - s_b) mod T]
//
// m13-copy clone: per block, 4 waves each issue VPT=4 independent, fully
// coalesced, 16B-aligned dwordx4 loads (phase 1), then block-uniform
// window-select + regular stores (phase 2). Reads realigned via a=(-s)&3
// (row-uniform). B-chunks overlap the next lane's A-chunk -> L1 hits.
// Regular (cached) stores: let our 100MB writeback defer outside the
// kernel window (testing the poison-drain-floor theory).

__device__ __forceinline__ f32x4 shuf(const f32x4 A, const f32x4 Bv, int a) {
    f32x4 r;
    switch (a) {  // block-uniform -> s_cbranch, no divergence
        case 1:  r.x = A.y; r.y = A.z; r.z = A.w; r.w = Bv.x; break;
        case 2:  r.x = A.z; r.y = A.w; r.z = Bv.x; r.w = Bv.y; break;
        default: r.x = A.w; r.y = Bv.x; r.z = Bv.y; r.w = Bv.z; break;
    }
    return r;
}

__global__ __launch_bounds__(BLOCK)
void roll_rows_copy(const float* __restrict__ x,
                    const int* __restrict__ shifts,
                    float* __restrict__ out,
                    int T, int T4) {
    const int b = blockIdx.y;
    const float* __restrict__ xr = x + (size_t)b * (size_t)T;
    float* __restrict__ outr = out + (size_t)b * (size_t)T;

    int s = shifts[b] % T;              // shifts in [0,1000); defensive
    if (s < 0) s += T;
    const int a = (-s) & 3;             // row-uniform misalignment (floats)
    int sa = s + a;                     // multiple of 4
    if (sa >= T) sa -= T;

    const int v0 = blockIdx.x * (BLOCK * VPT) + (int)threadIdx.x;

    int  vk[VPT], ik[VPT];
    bool pk[VPT];
#pragma unroll
    for (int k = 0; k < VPT; ++k) {
        vk[k] = v0 + k * BLOCK;
        pk[k] = vk[k] < T4;
        int i = (vk[k] << 2) - sa;
        if (i < 0) i += T;              // 16B-aligned, in [0, T-4]
        ik[k] = i;
    }

    // Phase 1: issue ALL loads back-to-back (up to 8 in flight).
    f32x4 A[VPT], Bv[VPT];
#pragma unroll
    for (int k = 0; k < VPT; ++k)
        if (pk[k]) A[k] = *reinterpret_cast<const f32x4*>(xr + ik[k]);
    if (a != 0) {
#pragma unroll
        for (int k = 0; k < VPT; ++k) {
            if (pk[k]) {
                int ib = ik[k] + 4;
                if (ib >= T) ib -= T;
                Bv[k] = *reinterpret_cast<const f32x4*>(xr + ib);  // mostly L1 hits
            }
        }
    }

    // Phase 2: block-uniform select + regular stores.
    if (a == 0) {
#pragma unroll
        for (int k = 0; k < VPT; ++k)
            if (pk[k]) *reinterpret_cast<f32x4*>(outr + (vk[k] << 2)) = A[k];
    } else {
#pragma unroll
        for (int k = 0; k < VPT; ++k)
            if (pk[k]) *reinterpret_cast<f32x4*>(outr + (vk[k] << 2)) = shuf(A[k], Bv[k], a);
    }
}

// Generic scalar fallback (T not divisible by 4).
__global__ void roll_rows_scalar(const float* __restrict__ x,
                                 const int* __restrict__ shifts,
                                 float* __restrict__ out,
                                 int T) {
    const int b = blockIdx.y;
    const int j = blockIdx.x * blockDim.x + threadIdx.x;
    if (j >= T) return;
    int s = shifts[b] % T;
    if (s < 0) s += T;
    int i = j - s;
    if (i < 0) i += T;
    out[(size_t)b * T + j] = x[(size_t)b * T + i];
}

extern "C" void kernel_launch(void* const* d_in, const int* in_sizes, int n_in,
                              void* d_out, int out_size, void* d_ws, size_t ws_size,
                              hipStream_t stream) {
    const float* x = (const float*)d_in[0];
    const int* shifts = (const int*)d_in[1];
    float* out = (float*)d_out;

    const int B = in_sizes[1];
    const int T = in_sizes[0] / B;

    if ((T & 3) == 0) {
        const int T4 = T / 4;
        dim3 block(BLOCK);
        dim3 grid((T4 + BLOCK * VPT - 1) / (BLOCK * VPT), B);
        roll_rows_copy<<<grid, block, 0, stream>>>(x, shifts, out, T, T4);
    } else {
        dim3 block(256);
        dim3 grid((T + 255) / 256, B);
        roll_rows_scalar<<<grid, block, 0, stream>>>(x, shifts, out, T);
    }
}